// Round 18
// baseline (233.652 us; speedup 1.0000x reference)
//
#include <hip/hip_runtime.h>
#include <hip/hip_bf16.h>
#include <math.h>

#define NA 50000
#define NE 800000
#define NBIN 50176            // NA rounded to 98*512
#define NCH 98
#define WPB 4                 // waves per block
#define NTILE 782             // 64-row tiles covering NA (edge + dense kernels)
#define SCAT_BLKS 1024
#define RF_BLKS 391

typedef float f32x4 __attribute__((ext_vector_type(4)));
typedef __bf16 bf16x8 __attribute__((ext_vector_type(8)));

__device__ __forceinline__ float ssp(float x) {
    float sp = (x > 15.0f) ? x : log1pf(__expf(x));
    return sp - 0.69314718f;
}

__device__ __forceinline__ uint32_t pkbf2(float a, float b) {
    union { __bf16 h[2]; uint32_t u; } x;
    x.h[0] = (__bf16)a; x.h[1] = (__bf16)b;
    return x.u;
}

// ---------------------------------------------------------------------------
// Pack weights once per launch into MFMA-B-fragment order (hi/lo bf16).
// ---------------------------------------------------------------------------
__global__ __launch_bounds__(256) void pack_weights(const float* __restrict__ Wa,
                                                    const float* __restrict__ W1,
                                                    const float* __restrict__ W2,
                                                    const float* __restrict__ Wf2,
                                                    __bf16* __restrict__ pWaH, __bf16* __restrict__ pWaL,
                                                    __bf16* __restrict__ pW1H, __bf16* __restrict__ pW1L,
                                                    __bf16* __restrict__ pW2H, __bf16* __restrict__ pW2L,
                                                    __bf16* __restrict__ pWf) {
    const int t = blockIdx.x * 256 + threadIdx.x;
    const int stride = gridDim.x * 256;
    for (int i = t; i < 16384; i += stride) {
        int k = i >> 7, n = i & 127;
        int addr = n * 128 + (((k >> 3) ^ (n & 15)) << 3) + (k & 7);
        float v; __bf16 h;
        v = Wa[i]; h = (__bf16)v; pWaH[addr] = h; pWaL[addr] = (__bf16)(v - (float)h);
        v = W1[i]; h = (__bf16)v; pW1H[addr] = h; pW1L[addr] = (__bf16)(v - (float)h);
        v = W2[i]; h = (__bf16)v; pW2H[addr] = h; pW2L[addr] = (__bf16)(v - (float)h);
    }
    for (int i = t; i < 8192; i += stride) {
        int k = i >> 7, n = i & 127;
        int addr = n * 64 + (((k >> 3) ^ (n & 7)) << 3) + (k & 7);
        pWf[addr] = (__bf16)Wf2[i];
    }
}

// ---------------------------------------------------------------------------
// CSR scans
// ---------------------------------------------------------------------------
__global__ __launch_bounds__(512) void scanA(const int* __restrict__ counts,
                                             int* __restrict__ chunk_sums) {
    __shared__ int red[512];
    int t = threadIdx.x;
    red[t] = counts[blockIdx.x * 512 + t];
    __syncthreads();
    for (int off = 256; off > 0; off >>= 1) {
        if (t < off) red[t] += red[t + off];
        __syncthreads();
    }
    if (t == 0) chunk_sums[blockIdx.x] = red[0];
}

__global__ __launch_bounds__(128) void scanB(int* __restrict__ chunk_sums) {
    __shared__ int s[128];
    int t = threadIdx.x;
    int v = (t < NCH) ? chunk_sums[t] : 0;
    s[t] = v;
    __syncthreads();
    for (int off = 1; off < 128; off <<= 1) {
        int add = (t >= off) ? s[t - off] : 0;
        __syncthreads();
        s[t] += add;
        __syncthreads();
    }
    if (t < NCH) chunk_sums[t] = s[t] - v;
}

__global__ __launch_bounds__(512) void scanC(const int* __restrict__ counts,
                                             const int* __restrict__ chunk_sums,
                                             int* __restrict__ row_ptr,
                                             int* __restrict__ cursor) {
    __shared__ int s[512];
    int t = threadIdx.x;
    int i = blockIdx.x * 512 + t;
    int v = counts[i];
    s[t] = v;
    __syncthreads();
    for (int off = 1; off < 512; off <<= 1) {
        int add = (t >= off) ? s[t - off] : 0;
        __syncthreads();
        s[t] += add;
        __syncthreads();
    }
    int excl = s[t] - v + chunk_sums[blockIdx.x];
    row_ptr[i] = excl;
    cursor[i]  = excl;
}

// ---------------------------------------------------------------------------
// rf GEMM body with pre-packed weights (output packed bf16).
// ---------------------------------------------------------------------------
__device__ __forceinline__ void rf_gemm_packed(const float* __restrict__ A,
                                               const __bf16* __restrict__ pWh,
                                               const __bf16* __restrict__ pWl,
                                               void* __restrict__ C, int M,
                                               int blk, int gridn,
                                               __bf16* sWhi, __bf16* sWlo) {
    const int tid = threadIdx.x;
    {
        const uint4* ph = (const uint4*)pWh;
        const uint4* pl = (const uint4*)pWl;
        uint4* dh = (uint4*)sWhi;
        uint4* dl = (uint4*)sWlo;
        for (int i = tid; i < 2048; i += 256) { dh[i] = ph[i]; dl[i] = pl[i]; }
    }
    __syncthreads();

    const int lane = tid & 63, w = tid >> 6;
    const int lrow = lane & 15, lgrp = lane >> 4;

    for (int base = blk * 64; base < M; base += gridn * 64) {
        const int row  = base + w * 16 + lrow;
        const int rowc = row < M ? row : M - 1;

        f32x4 acc[8];
        #pragma unroll
        for (int nt = 0; nt < 8; ++nt) acc[nt] = (f32x4){0.f, 0.f, 0.f, 0.f};

        #pragma unroll
        for (int ks = 0; ks < 4; ++ks) {
            int k0 = ks * 32 + lgrp * 8;
            float4 f0 = *(const float4*)&A[(size_t)rowc * 128 + k0];
            float4 f1 = *(const float4*)&A[(size_t)rowc * 128 + k0 + 4];
            float av[8] = {f0.x, f0.y, f0.z, f0.w, f1.x, f1.y, f1.z, f1.w};
            bf16x8 ah, al;
            #pragma unroll
            for (int j = 0; j < 8; ++j) {
                __bf16 h = (__bf16)av[j];
                ah[j] = h;
                al[j] = (__bf16)(av[j] - (float)h);
            }
            #pragma unroll
            for (int nt = 0; nt < 8; ++nt) {
                int n = nt * 16 + lrow;
                int addr = n * 128 + (((ks * 4 + lgrp) ^ (n & 15)) << 3);
                bf16x8 bh = *(const bf16x8*)&sWhi[addr];
                bf16x8 bl = *(const bf16x8*)&sWlo[addr];
                acc[nt] = __builtin_amdgcn_mfma_f32_16x16x32_bf16(ah, bh, acc[nt], 0, 0, 0);
                acc[nt] = __builtin_amdgcn_mfma_f32_16x16x32_bf16(ah, bl, acc[nt], 0, 0, 0);
                acc[nt] = __builtin_amdgcn_mfma_f32_16x16x32_bf16(al, bh, acc[nt], 0, 0, 0);
            }
        }

        const int orow = base + w * 16 + lgrp * 4;
        #pragma unroll
        for (int r = 0; r < 4; ++r) {
            if (orow + r < M) {
                #pragma unroll
                for (int nt = 0; nt < 8; ++nt) {
                    ((__hip_bfloat16*)C)[(size_t)(orow + r) * 128 + nt * 16 + lrow] =
                        __float2bfloat16(acc[nt][r]);
                }
            }
        }
    }
}

// ---------------------------------------------------------------------------
// Overlap kernel 1: hist (atomic-bound) || rf-GEMM tiles [0,391)
// ---------------------------------------------------------------------------
__global__ __launch_bounds__(256) void hist_rf(const int* __restrict__ a,
                                               int* __restrict__ counts,
                                               const float* __restrict__ r,
                                               const __bf16* __restrict__ pWaH,
                                               const __bf16* __restrict__ pWaL,
                                               void* __restrict__ rfb) {
    __shared__ __bf16 sWhi[128 * 128];
    __shared__ __bf16 sWlo[128 * 128];
    if (blockIdx.x < SCAT_BLKS) {
        for (int i = blockIdx.x * 256 + threadIdx.x; i < NE; i += SCAT_BLKS * 256) {
            int2 dp = ((const int2*)a)[i];
            atomicAdd(&counts[dp.x], 1);
        }
    } else {
        rf_gemm_packed(r, pWaH, pWaL, rfb, NA, blockIdx.x - SCAT_BLKS,
                       2 * RF_BLKS, sWhi, sWlo);
    }
}

// ---------------------------------------------------------------------------
// Overlap kernel 2: scatter (latency-bound) || rf-GEMM tiles [391,782)
// ---------------------------------------------------------------------------
__global__ __launch_bounds__(256) void scatter_rf(const int* __restrict__ a,
                                                  const float* __restrict__ e,
                                                  int* __restrict__ cursor,
                                                  uint32_t* __restrict__ sesq,
                                                  const float* __restrict__ r,
                                                  const __bf16* __restrict__ pWaH,
                                                  const __bf16* __restrict__ pWaL,
                                                  void* __restrict__ rfb) {
    __shared__ __bf16 sWhi[128 * 128];
    __shared__ __bf16 sWlo[128 * 128];
    if (blockIdx.x < SCAT_BLKS) {
        for (int i = blockIdx.x * 256 + threadIdx.x; i < NE; i += SCAT_BLKS * 256) {
            int2 dp = ((const int2*)a)[i];
            int pos = atomicAdd(&cursor[dp.x], 1);
            uint32_t eq = (uint32_t)(e[i] * 13107.0f + 0.5f);   // 65535/5
            sesq[pos] = (eq << 16) | (uint32_t)dp.y;
        }
    } else {
        rf_gemm_packed(r, pWaH, pWaL, rfb, NA,
                       blockIdx.x - SCAT_BLKS + RF_BLKS, 2 * RF_BLKS,
                       sWhi, sWlo);
    }
}

// ---------------------------------------------------------------------------
// Fused edge pipeline, TILE-ALIGNED: grid NTILE, block i's wave w owns dsts
// [i*64 + w*16, +16) -- exactly dense1's tile mapping, so dense1's reads of
// segb hit the same XCD's L2 that wrote them. 1-term gaussian, sesq register
// prefetch, segb (bf16-packed) in d_ws.
// ---------------------------------------------------------------------------
__global__ __launch_bounds__(256, 4) void edge_fused(const uint32_t* __restrict__ sesq,
                                                     const int* __restrict__ row_ptr,
                                                     const __bf16* __restrict__ pWf,
                                                     const float* __restrict__ bf2,
                                                     const uint32_t* __restrict__ rfb,
                                                     uint32_t* __restrict__ segb) {
    __shared__ __bf16 sWf[128 * 64];       // 16KB: Wf2^T bf16, k8 XOR swizzle
    __shared__ __bf16 sP[WPB][16 * 128];   // 4KB/wave bounce [e][f], XOR granules
    __shared__ float  sse[WPB][32];
    __shared__ int    sssrc[WPB][32];
    __shared__ int    ssrp[WPB][18];

    const int tid  = threadIdx.x;
    const int lane = tid & 63, w = tid >> 6;
    const int lrow = lane & 15, lgrp = lane >> 4;

    {
        const uint4* p = (const uint4*)pWf;
        uint4* d = (uint4*)sWf;
        for (int i = tid; i < 1024; i += 256) d[i] = p[i];
    }
    const int d_start = blockIdx.x * 64 + w * 16;
    const int d_end   = (d_start + 16 < NA) ? d_start + 16 : NA;
    const int dcount  = (d_end > d_start) ? (d_end - d_start) : 0;
    if (lane <= dcount)     ssrp[w][lane] = row_ptr[d_start + lane];
    if (lane == dcount + 1) ssrp[w][lane] = 0x7FFFFFFF;
    __syncthreads();

    float bv[8];
    #pragma unroll
    for (int nt = 0; nt < 8; ++nt) bv[nt] = bf2[nt * 16 + lrow];

    const float coeff = -0.5f * (63.0f / 5.0f) * (63.0f / 5.0f);
    float* sse_w  = sse[w];
    int*   ssrc_w = sssrc[w];
    int*   srp_w  = ssrp[w];
    __bf16* myP   = sP[w];
    const uint32_t* myPu = (const uint32_t*)myP;

    const int rp0 = srp_w[0], rend = (dcount > 0) ? srp_w[dcount] : srp_w[0];
    int ld = 0;
    int nextb = (dcount > 0) ? srp_w[1] : 0x7FFFFFFF;
    float racc0 = 0.0f, racc1 = 0.0f;

    uint32_t u_pref = 0;
    if (lane < 32 && rp0 + lane < rend) u_pref = sesq[rp0 + lane];

    for (int p = rp0; p < rend; p += 32) {
        const int cnt = (rend - p < 32) ? (rend - p) : 32;
        if (lane < 32) {
            sse_w[lane]  = (float)(u_pref >> 16) * (1.0f / 13107.0f);
            ssrc_w[lane] = (int)(u_pref & 0xFFFFu);
        }
        __builtin_amdgcn_wave_barrier();

        // prefetch NEXT chunk's sesq (1 register, in flight across the chunk)
        {
            int idx = p + 32 + lane;
            u_pref = (lane < 32 && idx < rend) ? sesq[idx] : 0u;
        }

        #pragma unroll
        for (int mt = 0; mt < 2; ++mt) {
            if (mt * 16 >= cnt) break;          // wave-uniform

            // gaussian A fragments (1-term bf16)
            float ev = sse_w[mt * 16 + lrow];
            bf16x8 ah[2];
            #pragma unroll
            for (int ks = 0; ks < 2; ++ks) {
                #pragma unroll
                for (int j = 0; j < 8; ++j) {
                    int k = ks * 32 + lgrp * 8 + j;
                    float dd = ev - (5.0f / 63.0f) * (float)k;
                    ah[ks][j] = (__bf16)__expf(coeff * dd * dd);
                }
            }

            // filter MFMA (1-term)
            f32x4 c[8];
            #pragma unroll
            for (int nt = 0; nt < 8; ++nt) c[nt] = (f32x4){0.f, 0.f, 0.f, 0.f};
            #pragma unroll
            for (int ks = 0; ks < 2; ++ks) {
                #pragma unroll
                for (int nt = 0; nt < 8; ++nt) {
                    int n = nt * 16 + lrow;
                    int addr = n * 64 + (((ks * 4 + lgrp) ^ (n & 7)) << 3);
                    bf16x8 bh = *(const bf16x8*)&sWf[addr];
                    c[nt] = __builtin_amdgcn_mfma_f32_16x16x32_bf16(ah[ks], bh, c[nt], 0, 0, 0);
                }
            }

            // bounce: bias + bf16 pack into wave-private LDS
            #pragma unroll
            for (int nt = 0; nt < 8; ++nt) {
                int f = nt * 16 + lrow;
                #pragma unroll
                for (int r = 0; r < 4; ++r) {
                    int e2 = lgrp * 4 + r;
                    float v = c[nt][r] + bv[nt];
                    myP[e2 * 128 + (((f >> 3) ^ (e2 & 7)) << 3) + (f & 7)] = (__bf16)v;
                }
            }
            __builtin_amdgcn_wave_barrier();

            // fully-batched consume: 16 bf16-rf gathers + 16 LDS reads in flight
            uint32_t rw[16];
            uint32_t uu[16];
            #pragma unroll
            for (int j = 0; j < 16; ++j) {
                int src = ssrc_w[mt * 16 + j];
                rw[j] = rfb[(size_t)src * 64 + lane];
                uu[j] = myPu[j * 64 + (((lane >> 2) ^ (j & 7)) << 2) + (lane & 3)];
            }
            #pragma unroll
            for (int j = 0; j < 16; ++j) {
                int gj = p + mt * 16 + j;
                if (gj < rend) {                       // wave-uniform
                    while (gj >= nextb) {              // wave-uniform
                        segb[(size_t)(d_start + ld) * 64 + lane] = pkbf2(racc0, racc1);
                        racc0 = 0.0f; racc1 = 0.0f;
                        ++ld;
                        nextb = srp_w[ld + 1];
                    }
                    racc0 = fmaf(__uint_as_float(rw[j] << 16),
                                 __uint_as_float(uu[j] << 16), racc0);
                    racc1 = fmaf(__uint_as_float(rw[j] & 0xFFFF0000u),
                                 __uint_as_float(uu[j] & 0xFFFF0000u), racc1);
                }
            }
            __builtin_amdgcn_wave_barrier();           // before myP reuse
        }
    }
    while (ld < dcount) {
        segb[(size_t)(d_start + ld) * 64 + lane] = pkbf2(racc0, racc1);
        racc0 = 0.0f; racc1 = 0.0f;
        ++ld;
    }
}

// ---------------------------------------------------------------------------
// Dense1: y1 = ssp(seg @ W1 + b1). Grid NTILE, block i <-> tile i == producer.
// ---------------------------------------------------------------------------
__global__ __launch_bounds__(256) void dense1(const uint32_t* __restrict__ segb,
                                              const __bf16* __restrict__ pW1H,
                                              const __bf16* __restrict__ pW1L,
                                              const float* __restrict__ b1,
                                              void* __restrict__ y1b) {
    __shared__ __bf16 sWhi[128 * 128];
    __shared__ __bf16 sWlo[128 * 128];
    const int tid = threadIdx.x;
    {
        const uint4* ph = (const uint4*)pW1H;
        const uint4* pl = (const uint4*)pW1L;
        uint4* dh = (uint4*)sWhi;
        uint4* dl = (uint4*)sWlo;
        for (int i = tid; i < 2048; i += 256) { dh[i] = ph[i]; dl[i] = pl[i]; }
    }
    __syncthreads();

    const int lane = tid & 63, w = tid >> 6;
    const int lrow = lane & 15, lgrp = lane >> 4;
    const __bf16* seg = (const __bf16*)segb;

    float bv[8];
    #pragma unroll
    for (int nt = 0; nt < 8; ++nt) bv[nt] = b1[nt * 16 + lrow];

    const int base = blockIdx.x * 64;
    const int row  = base + w * 16 + lrow;
    const int rowc = row < NA ? row : NA - 1;

    f32x4 acc[8];
    #pragma unroll
    for (int nt = 0; nt < 8; ++nt) acc[nt] = (f32x4){0.f, 0.f, 0.f, 0.f};

    #pragma unroll
    for (int ks = 0; ks < 4; ++ks) {
        int k0 = ks * 32 + lgrp * 8;
        bf16x8 ya = *(const bf16x8*)&seg[(size_t)rowc * 128 + k0];
        #pragma unroll
        for (int nt = 0; nt < 8; ++nt) {
            int n = nt * 16 + lrow;
            int addr = n * 128 + (((ks * 4 + lgrp) ^ (n & 15)) << 3);
            bf16x8 bh = *(const bf16x8*)&sWhi[addr];
            bf16x8 bl = *(const bf16x8*)&sWlo[addr];
            acc[nt] = __builtin_amdgcn_mfma_f32_16x16x32_bf16(ya, bh, acc[nt], 0, 0, 0);
            acc[nt] = __builtin_amdgcn_mfma_f32_16x16x32_bf16(ya, bl, acc[nt], 0, 0, 0);
        }
    }

    const int orow = base + w * 16 + lgrp * 4;
    #pragma unroll
    for (int r = 0; r < 4; ++r) {
        if (orow + r < NA) {
            #pragma unroll
            for (int nt = 0; nt < 8; ++nt) {
                float v = ssp(acc[nt][r] + bv[nt]);
                ((__hip_bfloat16*)y1b)[(size_t)(orow + r) * 128 + nt * 16 + lrow] =
                    __float2bfloat16(v);
            }
        }
    }
}

// ---------------------------------------------------------------------------
// Dense2: out = y1 @ W2 + b2. Only writer of d_out.
// ---------------------------------------------------------------------------
__global__ __launch_bounds__(256) void dense2(const void* __restrict__ y1b,
                                              const __bf16* __restrict__ pW2H,
                                              const __bf16* __restrict__ pW2L,
                                              const float* __restrict__ b2,
                                              float* __restrict__ out) {
    __shared__ __bf16 sWhi[128 * 128];
    __shared__ __bf16 sWlo[128 * 128];
    const int tid = threadIdx.x;
    {
        const uint4* ph = (const uint4*)pW2H;
        const uint4* pl = (const uint4*)pW2L;
        uint4* dh = (uint4*)sWhi;
        uint4* dl = (uint4*)sWlo;
        for (int i = tid; i < 2048; i += 256) { dh[i] = ph[i]; dl[i] = pl[i]; }
    }
    __syncthreads();

    const int lane = tid & 63, w = tid >> 6;
    const int lrow = lane & 15, lgrp = lane >> 4;
    const __bf16* y1 = (const __bf16*)y1b;

    float bv[8];
    #pragma unroll
    for (int nt = 0; nt < 8; ++nt) bv[nt] = b2[nt * 16 + lrow];

    const int base = blockIdx.x * 64;
    const int row  = base + w * 16 + lrow;
    const int rowc = row < NA ? row : NA - 1;

    f32x4 acc[8];
    #pragma unroll
    for (int nt = 0; nt < 8; ++nt) acc[nt] = (f32x4){0.f, 0.f, 0.f, 0.f};

    #pragma unroll
    for (int ks = 0; ks < 4; ++ks) {
        int k0 = ks * 32 + lgrp * 8;
        bf16x8 ya = *(const bf16x8*)&y1[(size_t)rowc * 128 + k0];
        #pragma unroll
        for (int nt = 0; nt < 8; ++nt) {
            int n = nt * 16 + lrow;
            int addr = n * 128 + (((ks * 4 + lgrp) ^ (n & 15)) << 3);
            bf16x8 bh = *(const bf16x8*)&sWhi[addr];
            bf16x8 bl = *(const bf16x8*)&sWlo[addr];
            acc[nt] = __builtin_amdgcn_mfma_f32_16x16x32_bf16(ya, bh, acc[nt], 0, 0, 0);
            acc[nt] = __builtin_amdgcn_mfma_f32_16x16x32_bf16(ya, bl, acc[nt], 0, 0, 0);
        }
    }

    const int orow = base + w * 16 + lgrp * 4;
    #pragma unroll
    for (int r = 0; r < 4; ++r) {
        if (orow + r < NA) {
            #pragma unroll
            for (int nt = 0; nt < 8; ++nt) {
                out[(size_t)(orow + r) * 128 + nt * 16 + lrow] = acc[nt][r] + bv[nt];
            }
        }
    }
}

extern "C" void kernel_launch(void* const* d_in, const int* in_sizes, int n_in,
                              void* d_out, int out_size, void* d_ws, size_t ws_size,
                              hipStream_t stream) {
    const float* r   = (const float*)d_in[0];
    const float* e   = (const float*)d_in[1];
    const float* Wf2 = (const float*)d_in[2];
    const float* bf2 = (const float*)d_in[3];
    const float* Wa  = (const float*)d_in[4];
    const float* W1  = (const float*)d_in[5];
    const float* b1  = (const float*)d_in[6];
    const float* W2  = (const float*)d_in[7];
    const float* b2  = (const float*)d_in[8];
    const int*   a   = (const int*)d_in[9];

    float* out = (float*)d_out;

    // workspace layout (4B words)
    uint32_t* rfb        = (uint32_t*)d_ws;              // rf bf16   [0, 3.2M)
    uint32_t* y1b        = (uint32_t*)d_ws + 3200000;    // y1 bf16   [3.2M, 6.4M)
    uint32_t* segb       = (uint32_t*)d_ws + 6400000;    // seg bf16  [6.4M, 9.6M)
    int*      counts     = (int*)d_ws + 9600000;         // NBIN
    int*      row_ptr    = counts + NBIN;                // NBIN
    int*      cursor     = row_ptr + NBIN;               // NBIN
    int*      chunk_sums = cursor + NBIN;                // 128
    uint32_t* sesq       = (uint32_t*)(chunk_sums + 128);// NE packed u16:u16
    __bf16*   pWaH       = (__bf16*)(sesq + NE);         // 6x16384 + 8192 bf16
    __bf16*   pWaL       = pWaH + 16384;
    __bf16*   pW1H       = pWaL + 16384;
    __bf16*   pW1L       = pW1H + 16384;
    __bf16*   pW2H       = pW1L + 16384;
    __bf16*   pW2L       = pW2H + 16384;
    __bf16*   pWf        = pW2L + 16384;

    hipMemsetAsync(counts, 0, NBIN * sizeof(int), stream);
    pack_weights<<<64, 256, 0, stream>>>(Wa, W1, W2, Wf2,
                                         pWaH, pWaL, pW1H, pW1L, pW2H, pW2L, pWf);

    // hist (atomic-bound) || rf-GEMM first half
    hist_rf<<<SCAT_BLKS + RF_BLKS, 256, 0, stream>>>(a, counts, r, pWaH, pWaL, rfb);
    scanA<<<NCH, 512, 0, stream>>>(counts, chunk_sums);
    scanB<<<1, 128, 0, stream>>>(chunk_sums);
    scanC<<<NCH, 512, 0, stream>>>(counts, chunk_sums, row_ptr, cursor);
    // scatter (latency-bound) || rf-GEMM second half
    scatter_rf<<<SCAT_BLKS + RF_BLKS, 256, 0, stream>>>(a, e, cursor, sesq,
                                                        r, pWaH, pWaL, rfb);

    // fused edge pipeline (TILE-ALIGNED with dense1: same grid, same mapping)
    edge_fused<<<NTILE, 256, 0, stream>>>(sesq, row_ptr, pWf, bf2, rfb, segb);

    // y1 = ssp(seg @ W1 + b1); out = y1 @ W2 + b2
    dense1<<<NTILE, 256, 0, stream>>>(segb, pW1H, pW1L, b1, y1b);
    dense2<<<NTILE, 256, 0, stream>>>(y1b, pW2H, pW2L, b2, out);
}

// Round 20
// 205.257 us; speedup vs baseline: 1.1383x; 1.1383x over previous
//
#include <hip/hip_runtime.h>
#include <hip/hip_bf16.h>
#include <math.h>

#define NA 50000
#define NE 800000
#define NBIN 50176            // NA rounded to 98*512
#define NCH 98
#define WPB 4                 // waves per block
#define NTILE 782             // 64-row tiles covering NA (dense kernels)
#define EGRID 1024            // edge blocks (4/CU)
#define NWAVES (EGRID * WPB)  // 4096 -> 12-13 dsts/wave
#define SCAT_BLKS 1024
#define RF_BLKS 391

typedef float f32x4 __attribute__((ext_vector_type(4)));
typedef __bf16 bf16x8 __attribute__((ext_vector_type(8)));

// softplus(x) - ln2, branch-free, hardware exp/log intrinsics only (no libm
// log1pf -- the library call is the prime suspect for dense1's 77us wall).
__device__ __forceinline__ float ssp(float x) {
    float z  = __expf(-fabsf(x));          // e^{-|x|}, v_exp_f32
    float lp = __logf(1.0f + z);           // log1p(e^{-|x|}), v_log_f32
    return fmaxf(x, 0.0f) + lp - 0.69314718f;
}

__device__ __forceinline__ uint32_t pkbf2(float a, float b) {
    union { __bf16 h[2]; uint32_t u; } x;
    x.h[0] = (__bf16)a; x.h[1] = (__bf16)b;
    return x.u;
}

// ---------------------------------------------------------------------------
// Pack weights once per launch into MFMA-B-fragment order (hi/lo bf16).
// ---------------------------------------------------------------------------
__global__ __launch_bounds__(256) void pack_weights(const float* __restrict__ Wa,
                                                    const float* __restrict__ W1,
                                                    const float* __restrict__ W2,
                                                    const float* __restrict__ Wf2,
                                                    __bf16* __restrict__ pWaH, __bf16* __restrict__ pWaL,
                                                    __bf16* __restrict__ pW1H, __bf16* __restrict__ pW1L,
                                                    __bf16* __restrict__ pW2H, __bf16* __restrict__ pW2L,
                                                    __bf16* __restrict__ pWf) {
    const int t = blockIdx.x * 256 + threadIdx.x;
    const int stride = gridDim.x * 256;
    for (int i = t; i < 16384; i += stride) {
        int k = i >> 7, n = i & 127;
        int addr = n * 128 + (((k >> 3) ^ (n & 15)) << 3) + (k & 7);
        float v; __bf16 h;
        v = Wa[i]; h = (__bf16)v; pWaH[addr] = h; pWaL[addr] = (__bf16)(v - (float)h);
        v = W1[i]; h = (__bf16)v; pW1H[addr] = h; pW1L[addr] = (__bf16)(v - (float)h);
        v = W2[i]; h = (__bf16)v; pW2H[addr] = h; pW2L[addr] = (__bf16)(v - (float)h);
    }
    for (int i = t; i < 8192; i += stride) {
        int k = i >> 7, n = i & 127;
        int addr = n * 64 + (((k >> 3) ^ (n & 7)) << 3) + (k & 7);
        pWf[addr] = (__bf16)Wf2[i];
    }
}

// ---------------------------------------------------------------------------
// CSR scans
// ---------------------------------------------------------------------------
__global__ __launch_bounds__(512) void scanA(const int* __restrict__ counts,
                                             int* __restrict__ chunk_sums) {
    __shared__ int red[512];
    int t = threadIdx.x;
    red[t] = counts[blockIdx.x * 512 + t];
    __syncthreads();
    for (int off = 256; off > 0; off >>= 1) {
        if (t < off) red[t] += red[t + off];
        __syncthreads();
    }
    if (t == 0) chunk_sums[blockIdx.x] = red[0];
}

__global__ __launch_bounds__(128) void scanB(int* __restrict__ chunk_sums) {
    __shared__ int s[128];
    int t = threadIdx.x;
    int v = (t < NCH) ? chunk_sums[t] : 0;
    s[t] = v;
    __syncthreads();
    for (int off = 1; off < 128; off <<= 1) {
        int add = (t >= off) ? s[t - off] : 0;
        __syncthreads();
        s[t] += add;
        __syncthreads();
    }
    if (t < NCH) chunk_sums[t] = s[t] - v;
}

__global__ __launch_bounds__(512) void scanC(const int* __restrict__ counts,
                                             const int* __restrict__ chunk_sums,
                                             int* __restrict__ row_ptr,
                                             int* __restrict__ cursor) {
    __shared__ int s[512];
    int t = threadIdx.x;
    int i = blockIdx.x * 512 + t;
    int v = counts[i];
    s[t] = v;
    __syncthreads();
    for (int off = 1; off < 512; off <<= 1) {
        int add = (t >= off) ? s[t - off] : 0;
        __syncthreads();
        s[t] += add;
        __syncthreads();
    }
    int excl = s[t] - v + chunk_sums[blockIdx.x];
    row_ptr[i] = excl;
    cursor[i]  = excl;
}

// ---------------------------------------------------------------------------
// rf GEMM body with pre-packed weights (output packed bf16).
// ---------------------------------------------------------------------------
__device__ __forceinline__ void rf_gemm_packed(const float* __restrict__ A,
                                               const __bf16* __restrict__ pWh,
                                               const __bf16* __restrict__ pWl,
                                               void* __restrict__ C, int M,
                                               int blk, int gridn,
                                               __bf16* sWhi, __bf16* sWlo) {
    const int tid = threadIdx.x;
    {
        const uint4* ph = (const uint4*)pWh;
        const uint4* pl = (const uint4*)pWl;
        uint4* dh = (uint4*)sWhi;
        uint4* dl = (uint4*)sWlo;
        for (int i = tid; i < 2048; i += 256) { dh[i] = ph[i]; dl[i] = pl[i]; }
    }
    __syncthreads();

    const int lane = tid & 63, w = tid >> 6;
    const int lrow = lane & 15, lgrp = lane >> 4;

    for (int base = blk * 64; base < M; base += gridn * 64) {
        const int row  = base + w * 16 + lrow;
        const int rowc = row < M ? row : M - 1;

        f32x4 acc[8];
        #pragma unroll
        for (int nt = 0; nt < 8; ++nt) acc[nt] = (f32x4){0.f, 0.f, 0.f, 0.f};

        #pragma unroll
        for (int ks = 0; ks < 4; ++ks) {
            int k0 = ks * 32 + lgrp * 8;
            float4 f0 = *(const float4*)&A[(size_t)rowc * 128 + k0];
            float4 f1 = *(const float4*)&A[(size_t)rowc * 128 + k0 + 4];
            float av[8] = {f0.x, f0.y, f0.z, f0.w, f1.x, f1.y, f1.z, f1.w};
            bf16x8 ah, al;
            #pragma unroll
            for (int j = 0; j < 8; ++j) {
                __bf16 h = (__bf16)av[j];
                ah[j] = h;
                al[j] = (__bf16)(av[j] - (float)h);
            }
            #pragma unroll
            for (int nt = 0; nt < 8; ++nt) {
                int n = nt * 16 + lrow;
                int addr = n * 128 + (((ks * 4 + lgrp) ^ (n & 15)) << 3);
                bf16x8 bh = *(const bf16x8*)&sWhi[addr];
                bf16x8 bl = *(const bf16x8*)&sWlo[addr];
                acc[nt] = __builtin_amdgcn_mfma_f32_16x16x32_bf16(ah, bh, acc[nt], 0, 0, 0);
                acc[nt] = __builtin_amdgcn_mfma_f32_16x16x32_bf16(ah, bl, acc[nt], 0, 0, 0);
                acc[nt] = __builtin_amdgcn_mfma_f32_16x16x32_bf16(al, bh, acc[nt], 0, 0, 0);
            }
        }

        const int orow = base + w * 16 + lgrp * 4;
        #pragma unroll
        for (int r = 0; r < 4; ++r) {
            if (orow + r < M) {
                #pragma unroll
                for (int nt = 0; nt < 8; ++nt) {
                    ((__hip_bfloat16*)C)[(size_t)(orow + r) * 128 + nt * 16 + lrow] =
                        __float2bfloat16(acc[nt][r]);
                }
            }
        }
    }
}

// ---------------------------------------------------------------------------
// Overlap kernel 1: hist (atomic-bound) || rf-GEMM tiles [0,391)
// ---------------------------------------------------------------------------
__global__ __launch_bounds__(256) void hist_rf(const int* __restrict__ a,
                                               int* __restrict__ counts,
                                               const float* __restrict__ r,
                                               const __bf16* __restrict__ pWaH,
                                               const __bf16* __restrict__ pWaL,
                                               void* __restrict__ rfb) {
    __shared__ __bf16 sWhi[128 * 128];
    __shared__ __bf16 sWlo[128 * 128];
    if (blockIdx.x < SCAT_BLKS) {
        for (int i = blockIdx.x * 256 + threadIdx.x; i < NE; i += SCAT_BLKS * 256) {
            int2 dp = ((const int2*)a)[i];
            atomicAdd(&counts[dp.x], 1);
        }
    } else {
        rf_gemm_packed(r, pWaH, pWaL, rfb, NA, blockIdx.x - SCAT_BLKS,
                       2 * RF_BLKS, sWhi, sWlo);
    }
}

// ---------------------------------------------------------------------------
// Overlap kernel 2: scatter (latency-bound) || rf-GEMM tiles [391,782)
// ---------------------------------------------------------------------------
__global__ __launch_bounds__(256) void scatter_rf(const int* __restrict__ a,
                                                  const float* __restrict__ e,
                                                  int* __restrict__ cursor,
                                                  uint32_t* __restrict__ sesq,
                                                  const float* __restrict__ r,
                                                  const __bf16* __restrict__ pWaH,
                                                  const __bf16* __restrict__ pWaL,
                                                  void* __restrict__ rfb) {
    __shared__ __bf16 sWhi[128 * 128];
    __shared__ __bf16 sWlo[128 * 128];
    if (blockIdx.x < SCAT_BLKS) {
        for (int i = blockIdx.x * 256 + threadIdx.x; i < NE; i += SCAT_BLKS * 256) {
            int2 dp = ((const int2*)a)[i];
            int pos = atomicAdd(&cursor[dp.x], 1);
            uint32_t eq = (uint32_t)(e[i] * 13107.0f + 0.5f);   // 65535/5
            sesq[pos] = (eq << 16) | (uint32_t)dp.y;
        }
    } else {
        rf_gemm_packed(r, pWaH, pWaL, rfb, NA,
                       blockIdx.x - SCAT_BLKS + RF_BLKS, 2 * RF_BLKS,
                       sWhi, sWlo);
    }
}

// ---------------------------------------------------------------------------
// Fused edge pipeline (R17 config). Balanced per-wave dst ranges, EGRID=1024.
// 1-term gaussian, sesq register prefetch, segb (bf16-packed) in d_ws.
// ---------------------------------------------------------------------------
__global__ __launch_bounds__(256, 4) void edge_fused(const uint32_t* __restrict__ sesq,
                                                     const int* __restrict__ row_ptr,
                                                     const __bf16* __restrict__ pWf,
                                                     const float* __restrict__ bf2,
                                                     const uint32_t* __restrict__ rfb,
                                                     uint32_t* __restrict__ segb) {
    __shared__ __bf16 sWf[128 * 64];       // 16KB: Wf2^T bf16, k8 XOR swizzle
    __shared__ __bf16 sP[WPB][16 * 128];   // 4KB/wave bounce [e][f], XOR granules
    __shared__ float  sse[WPB][32];
    __shared__ int    sssrc[WPB][32];
    __shared__ int    ssrp[WPB][16];

    const int tid  = threadIdx.x;
    const int lane = tid & 63, w = tid >> 6;
    const int lrow = lane & 15, lgrp = lane >> 4;

    {
        const uint4* p = (const uint4*)pWf;
        uint4* d = (uint4*)sWf;
        for (int i = tid; i < 1024; i += 256) d[i] = p[i];
    }
    const int wi      = blockIdx.x * WPB + w;
    const int d_start = (int)(((long long)wi * NA) / NWAVES);
    const int d_end   = (int)(((long long)(wi + 1) * NA) / NWAVES);
    const int dcount  = d_end - d_start;            // 12 or 13
    if (lane <= dcount)     ssrp[w][lane] = row_ptr[d_start + lane];
    if (lane == dcount + 1) ssrp[w][lane] = 0x7FFFFFFF;
    __syncthreads();

    float bv[8];
    #pragma unroll
    for (int nt = 0; nt < 8; ++nt) bv[nt] = bf2[nt * 16 + lrow];

    const float coeff = -0.5f * (63.0f / 5.0f) * (63.0f / 5.0f);
    float* sse_w  = sse[w];
    int*   ssrc_w = sssrc[w];
    int*   srp_w  = ssrp[w];
    __bf16* myP   = sP[w];
    const uint32_t* myPu = (const uint32_t*)myP;

    const int rp0 = srp_w[0], rend = srp_w[dcount];
    int ld = 0;
    int nextb = srp_w[1];
    float racc0 = 0.0f, racc1 = 0.0f;

    uint32_t u_pref = 0;
    if (lane < 32 && rp0 + lane < rend) u_pref = sesq[rp0 + lane];

    for (int p = rp0; p < rend; p += 32) {
        const int cnt = (rend - p < 32) ? (rend - p) : 32;
        if (lane < 32) {
            sse_w[lane]  = (float)(u_pref >> 16) * (1.0f / 13107.0f);
            ssrc_w[lane] = (int)(u_pref & 0xFFFFu);
        }
        __builtin_amdgcn_wave_barrier();

        // prefetch NEXT chunk's sesq (1 register, in flight across the chunk)
        {
            int idx = p + 32 + lane;
            u_pref = (lane < 32 && idx < rend) ? sesq[idx] : 0u;
        }

        #pragma unroll
        for (int mt = 0; mt < 2; ++mt) {
            if (mt * 16 >= cnt) break;          // wave-uniform

            // gaussian A fragments (1-term bf16)
            float ev = sse_w[mt * 16 + lrow];
            bf16x8 ah[2];
            #pragma unroll
            for (int ks = 0; ks < 2; ++ks) {
                #pragma unroll
                for (int j = 0; j < 8; ++j) {
                    int k = ks * 32 + lgrp * 8 + j;
                    float dd = ev - (5.0f / 63.0f) * (float)k;
                    ah[ks][j] = (__bf16)__expf(coeff * dd * dd);
                }
            }

            // filter MFMA (1-term)
            f32x4 c[8];
            #pragma unroll
            for (int nt = 0; nt < 8; ++nt) c[nt] = (f32x4){0.f, 0.f, 0.f, 0.f};
            #pragma unroll
            for (int ks = 0; ks < 2; ++ks) {
                #pragma unroll
                for (int nt = 0; nt < 8; ++nt) {
                    int n = nt * 16 + lrow;
                    int addr = n * 64 + (((ks * 4 + lgrp) ^ (n & 7)) << 3);
                    bf16x8 bh = *(const bf16x8*)&sWf[addr];
                    c[nt] = __builtin_amdgcn_mfma_f32_16x16x32_bf16(ah[ks], bh, c[nt], 0, 0, 0);
                }
            }

            // bounce: bias + bf16 pack into wave-private LDS
            #pragma unroll
            for (int nt = 0; nt < 8; ++nt) {
                int f = nt * 16 + lrow;
                #pragma unroll
                for (int r = 0; r < 4; ++r) {
                    int e2 = lgrp * 4 + r;
                    float v = c[nt][r] + bv[nt];
                    myP[e2 * 128 + (((f >> 3) ^ (e2 & 7)) << 3) + (f & 7)] = (__bf16)v;
                }
            }
            __builtin_amdgcn_wave_barrier();

            // fully-batched consume: 16 bf16-rf gathers + 16 LDS reads in flight
            uint32_t rw[16];
            uint32_t uu[16];
            #pragma unroll
            for (int j = 0; j < 16; ++j) {
                int src = ssrc_w[mt * 16 + j];
                rw[j] = rfb[(size_t)src * 64 + lane];
                uu[j] = myPu[j * 64 + (((lane >> 2) ^ (j & 7)) << 2) + (lane & 3)];
            }
            #pragma unroll
            for (int j = 0; j < 16; ++j) {
                int gj = p + mt * 16 + j;
                if (gj < rend) {                       // wave-uniform
                    while (gj >= nextb) {              // wave-uniform
                        segb[(size_t)(d_start + ld) * 64 + lane] = pkbf2(racc0, racc1);
                        racc0 = 0.0f; racc1 = 0.0f;
                        ++ld;
                        nextb = srp_w[ld + 1];
                    }
                    racc0 = fmaf(__uint_as_float(rw[j] << 16),
                                 __uint_as_float(uu[j] << 16), racc0);
                    racc1 = fmaf(__uint_as_float(rw[j] & 0xFFFF0000u),
                                 __uint_as_float(uu[j] & 0xFFFF0000u), racc1);
                }
            }
            __builtin_amdgcn_wave_barrier();           // before myP reuse
        }
    }
    while (ld < dcount) {
        segb[(size_t)(d_start + ld) * 64 + lane] = pkbf2(racc0, racc1);
        racc0 = 0.0f; racc1 = 0.0f;
        ++ld;
    }
}

// ---------------------------------------------------------------------------
// Dense1: y1 = ssp(seg @ W1 + b1). A = packed-bf16 seg (ws), direct bf16x8.
// ssp is branch-free hw exp/log.
// ---------------------------------------------------------------------------
__global__ __launch_bounds__(256) void dense1(const uint32_t* __restrict__ segb,
                                              const __bf16* __restrict__ pW1H,
                                              const __bf16* __restrict__ pW1L,
                                              const float* __restrict__ b1,
                                              void* __restrict__ y1b) {
    __shared__ __bf16 sWhi[128 * 128];
    __shared__ __bf16 sWlo[128 * 128];
    const int tid = threadIdx.x;
    {
        const uint4* ph = (const uint4*)pW1H;
        const uint4* pl = (const uint4*)pW1L;
        uint4* dh = (uint4*)sWhi;
        uint4* dl = (uint4*)sWlo;
        for (int i = tid; i < 2048; i += 256) { dh[i] = ph[i]; dl[i] = pl[i]; }
    }
    __syncthreads();

    const int lane = tid & 63, w = tid >> 6;
    const int lrow = lane & 15, lgrp = lane >> 4;
    const __bf16* seg = (const __bf16*)segb;

    float bv[8];
    #pragma unroll
    for (int nt = 0; nt < 8; ++nt) bv[nt] = b1[nt * 16 + lrow];

    const int base = blockIdx.x * 64;
    const int row  = base + w * 16 + lrow;
    const int rowc = row < NA ? row : NA - 1;

    f32x4 acc[8];
    #pragma unroll
    for (int nt = 0; nt < 8; ++nt) acc[nt] = (f32x4){0.f, 0.f, 0.f, 0.f};

    #pragma unroll
    for (int ks = 0; ks < 4; ++ks) {
        int k0 = ks * 32 + lgrp * 8;
        bf16x8 ya = *(const bf16x8*)&seg[(size_t)rowc * 128 + k0];
        #pragma unroll
        for (int nt = 0; nt < 8; ++nt) {
            int n = nt * 16 + lrow;
            int addr = n * 128 + (((ks * 4 + lgrp) ^ (n & 15)) << 3);
            bf16x8 bh = *(const bf16x8*)&sWhi[addr];
            bf16x8 bl = *(const bf16x8*)&sWlo[addr];
            acc[nt] = __builtin_amdgcn_mfma_f32_16x16x32_bf16(ya, bh, acc[nt], 0, 0, 0);
            acc[nt] = __builtin_amdgcn_mfma_f32_16x16x32_bf16(ya, bl, acc[nt], 0, 0, 0);
        }
    }

    const int orow = base + w * 16 + lgrp * 4;
    #pragma unroll
    for (int r = 0; r < 4; ++r) {
        if (orow + r < NA) {
            #pragma unroll
            for (int nt = 0; nt < 8; ++nt) {
                float v = ssp(acc[nt][r] + bv[nt]);
                ((__hip_bfloat16*)y1b)[(size_t)(orow + r) * 128 + nt * 16 + lrow] =
                    __float2bfloat16(v);
            }
        }
    }
}

// ---------------------------------------------------------------------------
// Dense2: out = y1 @ W2 + b2. Only writer of d_out.
// ---------------------------------------------------------------------------
__global__ __launch_bounds__(256) void dense2(const void* __restrict__ y1b,
                                              const __bf16* __restrict__ pW2H,
                                              const __bf16* __restrict__ pW2L,
                                              const float* __restrict__ b2,
                                              float* __restrict__ out) {
    __shared__ __bf16 sWhi[128 * 128];
    __shared__ __bf16 sWlo[128 * 128];
    const int tid = threadIdx.x;
    {
        const uint4* ph = (const uint4*)pW2H;
        const uint4* pl = (const uint4*)pW2L;
        uint4* dh = (uint4*)sWhi;
        uint4* dl = (uint4*)sWlo;
        for (int i = tid; i < 2048; i += 256) { dh[i] = ph[i]; dl[i] = pl[i]; }
    }
    __syncthreads();

    const int lane = tid & 63, w = tid >> 6;
    const int lrow = lane & 15, lgrp = lane >> 4;
    const __bf16* y1 = (const __bf16*)y1b;

    float bv[8];
    #pragma unroll
    for (int nt = 0; nt < 8; ++nt) bv[nt] = b2[nt * 16 + lrow];

    const int base = blockIdx.x * 64;
    const int row  = base + w * 16 + lrow;
    const int rowc = row < NA ? row : NA - 1;

    f32x4 acc[8];
    #pragma unroll
    for (int nt = 0; nt < 8; ++nt) acc[nt] = (f32x4){0.f, 0.f, 0.f, 0.f};

    #pragma unroll
    for (int ks = 0; ks < 4; ++ks) {
        int k0 = ks * 32 + lgrp * 8;
        bf16x8 ya = *(const bf16x8*)&y1[(size_t)rowc * 128 + k0];
        #pragma unroll
        for (int nt = 0; nt < 8; ++nt) {
            int n = nt * 16 + lrow;
            int addr = n * 128 + (((ks * 4 + lgrp) ^ (n & 15)) << 3);
            bf16x8 bh = *(const bf16x8*)&sWhi[addr];
            bf16x8 bl = *(const bf16x8*)&sWlo[addr];
            acc[nt] = __builtin_amdgcn_mfma_f32_16x16x32_bf16(ya, bh, acc[nt], 0, 0, 0);
            acc[nt] = __builtin_amdgcn_mfma_f32_16x16x32_bf16(ya, bl, acc[nt], 0, 0, 0);
        }
    }

    const int orow = base + w * 16 + lgrp * 4;
    #pragma unroll
    for (int r = 0; r < 4; ++r) {
        if (orow + r < NA) {
            #pragma unroll
            for (int nt = 0; nt < 8; ++nt) {
                out[(size_t)(orow + r) * 128 + nt * 16 + lrow] = acc[nt][r] + bv[nt];
            }
        }
    }
}

extern "C" void kernel_launch(void* const* d_in, const int* in_sizes, int n_in,
                              void* d_out, int out_size, void* d_ws, size_t ws_size,
                              hipStream_t stream) {
    const float* r   = (const float*)d_in[0];
    const float* e   = (const float*)d_in[1];
    const float* Wf2 = (const float*)d_in[2];
    const float* bf2 = (const float*)d_in[3];
    const float* Wa  = (const float*)d_in[4];
    const float* W1  = (const float*)d_in[5];
    const float* b1  = (const float*)d_in[6];
    const float* W2  = (const float*)d_in[7];
    const float* b2  = (const float*)d_in[8];
    const int*   a   = (const int*)d_in[9];

    float* out = (float*)d_out;

    // workspace layout (4B words)
    uint32_t* rfb        = (uint32_t*)d_ws;              // rf bf16   [0, 3.2M)
    uint32_t* y1b        = (uint32_t*)d_ws + 3200000;    // y1 bf16   [3.2M, 6.4M)
    uint32_t* segb       = (uint32_t*)d_ws + 6400000;    // seg bf16  [6.4M, 9.6M)
    int*      counts     = (int*)d_ws + 9600000;         // NBIN
    int*      row_ptr    = counts + NBIN;                // NBIN
    int*      cursor     = row_ptr + NBIN;               // NBIN
    int*      chunk_sums = cursor + NBIN;                // 128
    uint32_t* sesq       = (uint32_t*)(chunk_sums + 128);// NE packed u16:u16
    __bf16*   pWaH       = (__bf16*)(sesq + NE);         // 6x16384 + 8192 bf16
    __bf16*   pWaL       = pWaH + 16384;
    __bf16*   pW1H       = pWaL + 16384;
    __bf16*   pW1L       = pW1H + 16384;
    __bf16*   pW2H       = pW1L + 16384;
    __bf16*   pW2L       = pW2H + 16384;
    __bf16*   pWf        = pW2L + 16384;

    (void)hipMemsetAsync(counts, 0, NBIN * sizeof(int), stream);
    pack_weights<<<64, 256, 0, stream>>>(Wa, W1, W2, Wf2,
                                         pWaH, pWaL, pW1H, pW1L, pW2H, pW2L, pWf);

    // hist (atomic-bound) || rf-GEMM first half
    hist_rf<<<SCAT_BLKS + RF_BLKS, 256, 0, stream>>>(a, counts, r, pWaH, pWaL, rfb);
    scanA<<<NCH, 512, 0, stream>>>(counts, chunk_sums);
    scanB<<<1, 128, 0, stream>>>(chunk_sums);
    scanC<<<NCH, 512, 0, stream>>>(counts, chunk_sums, row_ptr, cursor);
    // scatter (latency-bound) || rf-GEMM second half
    scatter_rf<<<SCAT_BLKS + RF_BLKS, 256, 0, stream>>>(a, e, cursor, sesq,
                                                        r, pWaH, pWaL, rfb);

    // fused edge pipeline (R17 config: balanced waves, 1-term g, segb in ws)
    edge_fused<<<EGRID, 256, 0, stream>>>(sesq, row_ptr, pWf, bf2, rfb, segb);

    // y1 = ssp(seg @ W1 + b1); out = y1 @ W2 + b2
    dense1<<<NTILE, 256, 0, stream>>>(segb, pW1H, pW1L, b1, y1b);
    dense2<<<NTILE, 256, 0, stream>>>(y1b, pW2H, pW2L, b2, out);
}

// Round 21
// 196.531 us; speedup vs baseline: 1.1889x; 1.0444x over previous
//
#include <hip/hip_runtime.h>
#include <hip/hip_bf16.h>
#include <math.h>

#define NA 50000
#define NE 800000
#define NBIN 50176            // NA rounded to 98*512
#define NCH 98
#define WPB 4                 // waves per block
#define NTILE 782             // 64-row tiles covering NA (dense kernels)
#define EGRID 2048            // edge blocks (8/CU)
#define NWAVES (EGRID * WPB)  // 8192 -> 6-7 dsts/wave
#define SCAT_BLKS 1024
#define RF_BLKS 391
#define TAB_BLKS 256          // 16384 table rows / 64
#define NTAB 16384            // 14-bit quantized e -> filter table rows

typedef float f32x4 __attribute__((ext_vector_type(4)));
typedef __bf16 bf16x8 __attribute__((ext_vector_type(8)));

// softplus(x) - ln2, branch-free hardware exp/log (R20-proven: libm log1pf
// was dense1's 77us wall).
__device__ __forceinline__ float ssp(float x) {
    float z  = __expf(-fabsf(x));
    float lp = __logf(1.0f + z);
    return fmaxf(x, 0.0f) + lp - 0.69314718f;
}

__device__ __forceinline__ uint32_t pkbf2(float a, float b) {
    union { __bf16 h[2]; uint32_t u; } x;
    x.h[0] = (__bf16)a; x.h[1] = (__bf16)b;
    return x.u;
}

// ---------------------------------------------------------------------------
// Pack weights once per launch into MFMA-B-fragment order (hi/lo bf16).
// ---------------------------------------------------------------------------
__global__ __launch_bounds__(256) void pack_weights(const float* __restrict__ Wa,
                                                    const float* __restrict__ W1,
                                                    const float* __restrict__ W2,
                                                    const float* __restrict__ Wf2,
                                                    __bf16* __restrict__ pWaH, __bf16* __restrict__ pWaL,
                                                    __bf16* __restrict__ pW1H, __bf16* __restrict__ pW1L,
                                                    __bf16* __restrict__ pW2H, __bf16* __restrict__ pW2L,
                                                    __bf16* __restrict__ pWf) {
    const int t = blockIdx.x * 256 + threadIdx.x;
    const int stride = gridDim.x * 256;
    for (int i = t; i < 16384; i += stride) {
        int k = i >> 7, n = i & 127;
        int addr = n * 128 + (((k >> 3) ^ (n & 15)) << 3) + (k & 7);
        float v; __bf16 h;
        v = Wa[i]; h = (__bf16)v; pWaH[addr] = h; pWaL[addr] = (__bf16)(v - (float)h);
        v = W1[i]; h = (__bf16)v; pW1H[addr] = h; pW1L[addr] = (__bf16)(v - (float)h);
        v = W2[i]; h = (__bf16)v; pW2H[addr] = h; pW2L[addr] = (__bf16)(v - (float)h);
    }
    for (int i = t; i < 8192; i += stride) {
        int k = i >> 7, n = i & 127;
        int addr = n * 64 + (((k >> 3) ^ (n & 7)) << 3) + (k & 7);
        pWf[addr] = (__bf16)Wf2[i];
    }
}

// ---------------------------------------------------------------------------
// CSR scans
// ---------------------------------------------------------------------------
__global__ __launch_bounds__(512) void scanA(const int* __restrict__ counts,
                                             int* __restrict__ chunk_sums) {
    __shared__ int red[512];
    int t = threadIdx.x;
    red[t] = counts[blockIdx.x * 512 + t];
    __syncthreads();
    for (int off = 256; off > 0; off >>= 1) {
        if (t < off) red[t] += red[t + off];
        __syncthreads();
    }
    if (t == 0) chunk_sums[blockIdx.x] = red[0];
}

__global__ __launch_bounds__(128) void scanB(int* __restrict__ chunk_sums) {
    __shared__ int s[128];
    int t = threadIdx.x;
    int v = (t < NCH) ? chunk_sums[t] : 0;
    s[t] = v;
    __syncthreads();
    for (int off = 1; off < 128; off <<= 1) {
        int add = (t >= off) ? s[t - off] : 0;
        __syncthreads();
        s[t] += add;
        __syncthreads();
    }
    if (t < NCH) chunk_sums[t] = s[t] - v;
}

__global__ __launch_bounds__(512) void scanC(const int* __restrict__ counts,
                                             const int* __restrict__ chunk_sums,
                                             int* __restrict__ row_ptr,
                                             int* __restrict__ cursor) {
    __shared__ int s[512];
    int t = threadIdx.x;
    int i = blockIdx.x * 512 + t;
    int v = counts[i];
    s[t] = v;
    __syncthreads();
    for (int off = 1; off < 512; off <<= 1) {
        int add = (t >= off) ? s[t - off] : 0;
        __syncthreads();
        s[t] += add;
        __syncthreads();
    }
    int excl = s[t] - v + chunk_sums[blockIdx.x];
    row_ptr[i] = excl;
    cursor[i]  = excl;
}

// ---------------------------------------------------------------------------
// rf GEMM body with pre-packed weights (output packed bf16).
// ---------------------------------------------------------------------------
__device__ __forceinline__ void rf_gemm_packed(const float* __restrict__ A,
                                               const __bf16* __restrict__ pWh,
                                               const __bf16* __restrict__ pWl,
                                               void* __restrict__ C, int M,
                                               int blk, int gridn,
                                               __bf16* sWhi, __bf16* sWlo) {
    const int tid = threadIdx.x;
    {
        const uint4* ph = (const uint4*)pWh;
        const uint4* pl = (const uint4*)pWl;
        uint4* dh = (uint4*)sWhi;
        uint4* dl = (uint4*)sWlo;
        for (int i = tid; i < 2048; i += 256) { dh[i] = ph[i]; dl[i] = pl[i]; }
    }
    __syncthreads();

    const int lane = tid & 63, w = tid >> 6;
    const int lrow = lane & 15, lgrp = lane >> 4;

    for (int base = blk * 64; base < M; base += gridn * 64) {
        const int row  = base + w * 16 + lrow;
        const int rowc = row < M ? row : M - 1;

        f32x4 acc[8];
        #pragma unroll
        for (int nt = 0; nt < 8; ++nt) acc[nt] = (f32x4){0.f, 0.f, 0.f, 0.f};

        #pragma unroll
        for (int ks = 0; ks < 4; ++ks) {
            int k0 = ks * 32 + lgrp * 8;
            float4 f0 = *(const float4*)&A[(size_t)rowc * 128 + k0];
            float4 f1 = *(const float4*)&A[(size_t)rowc * 128 + k0 + 4];
            float av[8] = {f0.x, f0.y, f0.z, f0.w, f1.x, f1.y, f1.z, f1.w};
            bf16x8 ah, al;
            #pragma unroll
            for (int j = 0; j < 8; ++j) {
                __bf16 h = (__bf16)av[j];
                ah[j] = h;
                al[j] = (__bf16)(av[j] - (float)h);
            }
            #pragma unroll
            for (int nt = 0; nt < 8; ++nt) {
                int n = nt * 16 + lrow;
                int addr = n * 128 + (((ks * 4 + lgrp) ^ (n & 15)) << 3);
                bf16x8 bh = *(const bf16x8*)&sWhi[addr];
                bf16x8 bl = *(const bf16x8*)&sWlo[addr];
                acc[nt] = __builtin_amdgcn_mfma_f32_16x16x32_bf16(ah, bh, acc[nt], 0, 0, 0);
                acc[nt] = __builtin_amdgcn_mfma_f32_16x16x32_bf16(ah, bl, acc[nt], 0, 0, 0);
                acc[nt] = __builtin_amdgcn_mfma_f32_16x16x32_bf16(al, bh, acc[nt], 0, 0, 0);
            }
        }

        const int orow = base + w * 16 + lgrp * 4;
        #pragma unroll
        for (int r = 0; r < 4; ++r) {
            if (orow + r < M) {
                #pragma unroll
                for (int nt = 0; nt < 8; ++nt) {
                    ((__hip_bfloat16*)C)[(size_t)(orow + r) * 128 + nt * 16 + lrow] =
                        __float2bfloat16(acc[nt][r]);
                }
            }
        }
    }
}

// ---------------------------------------------------------------------------
// Filter-table build: Wtab[idx][f] = bf16( g(e_idx) @ Wf2_bf16 + bf2 ),
// e_idx = (idx*4 + 1.5)/13107 (center of the 4 u16-quant codes mapping here).
// Identical math to the former per-edge filter MFMA path.
// ---------------------------------------------------------------------------
__device__ __forceinline__ void tab_build(const __bf16* __restrict__ pWf,
                                          const float* __restrict__ bf2,
                                          __hip_bfloat16* __restrict__ wtab,
                                          int blk, __bf16* sWf) {
    const int tid = threadIdx.x;
    {
        const uint4* p = (const uint4*)pWf;
        uint4* d = (uint4*)sWf;
        for (int i = tid; i < 1024; i += 256) d[i] = p[i];
    }
    __syncthreads();

    const int lane = tid & 63, w = tid >> 6;
    const int lrow = lane & 15, lgrp = lane >> 4;

    float bv[8];
    #pragma unroll
    for (int nt = 0; nt < 8; ++nt) bv[nt] = bf2[nt * 16 + lrow];

    const float coeff = -0.5f * (63.0f / 5.0f) * (63.0f / 5.0f);
    const int row = blk * 64 + w * 16 + lrow;           // A-fragment row
    const float ev = ((float)row * 4.0f + 1.5f) * (1.0f / 13107.0f);

    bf16x8 ah[2];
    #pragma unroll
    for (int ks = 0; ks < 2; ++ks) {
        #pragma unroll
        for (int j = 0; j < 8; ++j) {
            int k = ks * 32 + lgrp * 8 + j;
            float dd = ev - (5.0f / 63.0f) * (float)k;
            ah[ks][j] = (__bf16)__expf(coeff * dd * dd);
        }
    }

    f32x4 c[8];
    #pragma unroll
    for (int nt = 0; nt < 8; ++nt) c[nt] = (f32x4){0.f, 0.f, 0.f, 0.f};
    #pragma unroll
    for (int ks = 0; ks < 2; ++ks) {
        #pragma unroll
        for (int nt = 0; nt < 8; ++nt) {
            int n = nt * 16 + lrow;
            int addr = n * 64 + (((ks * 4 + lgrp) ^ (n & 7)) << 3);
            bf16x8 bh = *(const bf16x8*)&sWf[addr];
            c[nt] = __builtin_amdgcn_mfma_f32_16x16x32_bf16(ah[ks], bh, c[nt], 0, 0, 0);
        }
    }

    const int orow = blk * 64 + w * 16 + lgrp * 4;
    #pragma unroll
    for (int r = 0; r < 4; ++r) {
        #pragma unroll
        for (int nt = 0; nt < 8; ++nt) {
            wtab[(size_t)(orow + r) * 128 + nt * 16 + lrow] =
                __float2bfloat16(c[nt][r] + bv[nt]);
        }
    }
}

// ---------------------------------------------------------------------------
// Overlap kernel 1: hist (atomic-bound) || rf-GEMM tiles [0,391) || table build
// ---------------------------------------------------------------------------
__global__ __launch_bounds__(256) void hist_rf(const int* __restrict__ a,
                                               int* __restrict__ counts,
                                               const float* __restrict__ r,
                                               const __bf16* __restrict__ pWaH,
                                               const __bf16* __restrict__ pWaL,
                                               void* __restrict__ rfb,
                                               const __bf16* __restrict__ pWf,
                                               const float* __restrict__ bf2,
                                               __hip_bfloat16* __restrict__ wtab) {
    __shared__ __bf16 sWhi[128 * 128];
    __shared__ __bf16 sWlo[128 * 128];
    if (blockIdx.x < SCAT_BLKS) {
        for (int i = blockIdx.x * 256 + threadIdx.x; i < NE; i += SCAT_BLKS * 256) {
            int2 dp = ((const int2*)a)[i];
            atomicAdd(&counts[dp.x], 1);
        }
    } else if (blockIdx.x < SCAT_BLKS + RF_BLKS) {
        rf_gemm_packed(r, pWaH, pWaL, rfb, NA, blockIdx.x - SCAT_BLKS,
                       2 * RF_BLKS, sWhi, sWlo);
    } else {
        tab_build(pWf, bf2, wtab, blockIdx.x - SCAT_BLKS - RF_BLKS, sWhi);
    }
}

// ---------------------------------------------------------------------------
// Overlap kernel 2: scatter (latency-bound) || rf-GEMM tiles [391,782)
// ---------------------------------------------------------------------------
__global__ __launch_bounds__(256) void scatter_rf(const int* __restrict__ a,
                                                  const float* __restrict__ e,
                                                  int* __restrict__ cursor,
                                                  uint32_t* __restrict__ sesq,
                                                  const float* __restrict__ r,
                                                  const __bf16* __restrict__ pWaH,
                                                  const __bf16* __restrict__ pWaL,
                                                  void* __restrict__ rfb) {
    __shared__ __bf16 sWhi[128 * 128];
    __shared__ __bf16 sWlo[128 * 128];
    if (blockIdx.x < SCAT_BLKS) {
        for (int i = blockIdx.x * 256 + threadIdx.x; i < NE; i += SCAT_BLKS * 256) {
            int2 dp = ((const int2*)a)[i];
            int pos = atomicAdd(&cursor[dp.x], 1);
            uint32_t eq = (uint32_t)(e[i] * 13107.0f + 0.5f);   // 65535/5
            sesq[pos] = (eq << 16) | (uint32_t)dp.y;
        }
    } else {
        rf_gemm_packed(r, pWaH, pWaL, rfb, NA,
                       blockIdx.x - SCAT_BLKS + RF_BLKS, 2 * RF_BLKS,
                       sWhi, sWlo);
    }
}

// ---------------------------------------------------------------------------
// Edge pipeline v2: pure gather-fma. Per edge: coalesced rfb row + wtab row
// (both packed bf16, u32/lane) -> 2 fma into running dst accumulators ->
// boundary-walk flush. No MFMA, no expf, no bounce LDS. 8 blocks/CU.
// ---------------------------------------------------------------------------
__global__ __launch_bounds__(256, 8) void edge_fused(const uint32_t* __restrict__ sesq,
                                                     const int* __restrict__ row_ptr,
                                                     const uint32_t* __restrict__ wtab,
                                                     const uint32_t* __restrict__ rfb,
                                                     uint32_t* __restrict__ segb) {
    __shared__ int sssrc[WPB][32];
    __shared__ int ssidx[WPB][32];
    __shared__ int ssrp[WPB][12];

    const int tid  = threadIdx.x;
    const int lane = tid & 63, w = tid >> 6;

    const int wi      = blockIdx.x * WPB + w;
    const int d_start = (int)(((long long)wi * NA) / NWAVES);
    const int d_end   = (int)(((long long)(wi + 1) * NA) / NWAVES);
    const int dcount  = d_end - d_start;            // 6 or 7
    if (lane <= dcount)     ssrp[w][lane] = row_ptr[d_start + lane];
    if (lane == dcount + 1) ssrp[w][lane] = 0x7FFFFFFF;
    __syncthreads();

    int* srp_w  = ssrp[w];
    int* ssrc_w = sssrc[w];
    int* sidx_w = ssidx[w];

    const int rp0 = srp_w[0], rend = srp_w[dcount];
    int ld = 0;
    int nextb = srp_w[1];
    float racc0 = 0.0f, racc1 = 0.0f;

    uint32_t u_pref = 0;
    if (lane < 32 && rp0 + lane < rend) u_pref = sesq[rp0 + lane];

    for (int p = rp0; p < rend; p += 32) {
        const int cnt = (rend - p < 32) ? (rend - p) : 32;
        if (lane < 32) {
            ssrc_w[lane] = (int)(u_pref & 0xFFFFu);
            sidx_w[lane] = (int)(u_pref >> 18);     // 14-bit table row
        }
        __builtin_amdgcn_wave_barrier();

        // prefetch NEXT chunk's sesq (1 register, in flight across the chunk)
        {
            int idx = p + 32 + lane;
            u_pref = (lane < 32 && idx < rend) ? sesq[idx] : 0u;
        }

        #pragma unroll
        for (int half = 0; half < 2; ++half) {
            if (half * 16 >= cnt) break;            // wave-uniform

            // batched: 16 rfb rows + 16 wtab rows in flight
            uint32_t rw[16], tw[16];
            #pragma unroll
            for (int j = 0; j < 16; ++j) {
                int jj = half * 16 + j;
                rw[j] = rfb[(size_t)ssrc_w[jj] * 64 + lane];
                tw[j] = wtab[(size_t)sidx_w[jj] * 64 + lane];
            }
            #pragma unroll
            for (int j = 0; j < 16; ++j) {
                int gj = p + half * 16 + j;
                if (gj < rend) {                    // wave-uniform
                    while (gj >= nextb) {           // wave-uniform
                        segb[(size_t)(d_start + ld) * 64 + lane] = pkbf2(racc0, racc1);
                        racc0 = 0.0f; racc1 = 0.0f;
                        ++ld;
                        nextb = srp_w[ld + 1];
                    }
                    racc0 = fmaf(__uint_as_float(rw[j] << 16),
                                 __uint_as_float(tw[j] << 16), racc0);
                    racc1 = fmaf(__uint_as_float(rw[j] & 0xFFFF0000u),
                                 __uint_as_float(tw[j] & 0xFFFF0000u), racc1);
                }
            }
        }
        __builtin_amdgcn_wave_barrier();            // before sssrc/ssidx reuse
    }
    while (ld < dcount) {
        segb[(size_t)(d_start + ld) * 64 + lane] = pkbf2(racc0, racc1);
        racc0 = 0.0f; racc1 = 0.0f;
        ++ld;
    }
}

// ---------------------------------------------------------------------------
// Dense1: y1 = ssp(seg @ W1 + b1). A = packed-bf16 seg (ws), direct bf16x8.
// ---------------------------------------------------------------------------
__global__ __launch_bounds__(256) void dense1(const uint32_t* __restrict__ segb,
                                              const __bf16* __restrict__ pW1H,
                                              const __bf16* __restrict__ pW1L,
                                              const float* __restrict__ b1,
                                              void* __restrict__ y1b) {
    __shared__ __bf16 sWhi[128 * 128];
    __shared__ __bf16 sWlo[128 * 128];
    const int tid = threadIdx.x;
    {
        const uint4* ph = (const uint4*)pW1H;
        const uint4* pl = (const uint4*)pW1L;
        uint4* dh = (uint4*)sWhi;
        uint4* dl = (uint4*)sWlo;
        for (int i = tid; i < 2048; i += 256) { dh[i] = ph[i]; dl[i] = pl[i]; }
    }
    __syncthreads();

    const int lane = tid & 63, w = tid >> 6;
    const int lrow = lane & 15, lgrp = lane >> 4;
    const __bf16* seg = (const __bf16*)segb;

    float bv[8];
    #pragma unroll
    for (int nt = 0; nt < 8; ++nt) bv[nt] = b1[nt * 16 + lrow];

    const int base = blockIdx.x * 64;
    const int row  = base + w * 16 + lrow;
    const int rowc = row < NA ? row : NA - 1;

    f32x4 acc[8];
    #pragma unroll
    for (int nt = 0; nt < 8; ++nt) acc[nt] = (f32x4){0.f, 0.f, 0.f, 0.f};

    #pragma unroll
    for (int ks = 0; ks < 4; ++ks) {
        int k0 = ks * 32 + lgrp * 8;
        bf16x8 ya = *(const bf16x8*)&seg[(size_t)rowc * 128 + k0];
        #pragma unroll
        for (int nt = 0; nt < 8; ++nt) {
            int n = nt * 16 + lrow;
            int addr = n * 128 + (((ks * 4 + lgrp) ^ (n & 15)) << 3);
            bf16x8 bh = *(const bf16x8*)&sWhi[addr];
            bf16x8 bl = *(const bf16x8*)&sWlo[addr];
            acc[nt] = __builtin_amdgcn_mfma_f32_16x16x32_bf16(ya, bh, acc[nt], 0, 0, 0);
            acc[nt] = __builtin_amdgcn_mfma_f32_16x16x32_bf16(ya, bl, acc[nt], 0, 0, 0);
        }
    }

    const int orow = base + w * 16 + lgrp * 4;
    #pragma unroll
    for (int r = 0; r < 4; ++r) {
        if (orow + r < NA) {
            #pragma unroll
            for (int nt = 0; nt < 8; ++nt) {
                float v = ssp(acc[nt][r] + bv[nt]);
                ((__hip_bfloat16*)y1b)[(size_t)(orow + r) * 128 + nt * 16 + lrow] =
                    __float2bfloat16(v);
            }
        }
    }
}

// ---------------------------------------------------------------------------
// Dense2: out = y1 @ W2 + b2. Only writer of d_out (after wtab is dead).
// ---------------------------------------------------------------------------
__global__ __launch_bounds__(256) void dense2(const void* __restrict__ y1b,
                                              const __bf16* __restrict__ pW2H,
                                              const __bf16* __restrict__ pW2L,
                                              const float* __restrict__ b2,
                                              float* __restrict__ out) {
    __shared__ __bf16 sWhi[128 * 128];
    __shared__ __bf16 sWlo[128 * 128];
    const int tid = threadIdx.x;
    {
        const uint4* ph = (const uint4*)pW2H;
        const uint4* pl = (const uint4*)pW2L;
        uint4* dh = (uint4*)sWhi;
        uint4* dl = (uint4*)sWlo;
        for (int i = tid; i < 2048; i += 256) { dh[i] = ph[i]; dl[i] = pl[i]; }
    }
    __syncthreads();

    const int lane = tid & 63, w = tid >> 6;
    const int lrow = lane & 15, lgrp = lane >> 4;
    const __bf16* y1 = (const __bf16*)y1b;

    float bv[8];
    #pragma unroll
    for (int nt = 0; nt < 8; ++nt) bv[nt] = b2[nt * 16 + lrow];

    const int base = blockIdx.x * 64;
    const int row  = base + w * 16 + lrow;
    const int rowc = row < NA ? row : NA - 1;

    f32x4 acc[8];
    #pragma unroll
    for (int nt = 0; nt < 8; ++nt) acc[nt] = (f32x4){0.f, 0.f, 0.f, 0.f};

    #pragma unroll
    for (int ks = 0; ks < 4; ++ks) {
        int k0 = ks * 32 + lgrp * 8;
        bf16x8 ya = *(const bf16x8*)&y1[(size_t)rowc * 128 + k0];
        #pragma unroll
        for (int nt = 0; nt < 8; ++nt) {
            int n = nt * 16 + lrow;
            int addr = n * 128 + (((ks * 4 + lgrp) ^ (n & 15)) << 3);
            bf16x8 bh = *(const bf16x8*)&sWhi[addr];
            bf16x8 bl = *(const bf16x8*)&sWlo[addr];
            acc[nt] = __builtin_amdgcn_mfma_f32_16x16x32_bf16(ya, bh, acc[nt], 0, 0, 0);
            acc[nt] = __builtin_amdgcn_mfma_f32_16x16x32_bf16(ya, bl, acc[nt], 0, 0, 0);
        }
    }

    const int orow = base + w * 16 + lgrp * 4;
    #pragma unroll
    for (int r = 0; r < 4; ++r) {
        if (orow + r < NA) {
            #pragma unroll
            for (int nt = 0; nt < 8; ++nt) {
                out[(size_t)(orow + r) * 128 + nt * 16 + lrow] = acc[nt][r] + bv[nt];
            }
        }
    }
}

extern "C" void kernel_launch(void* const* d_in, const int* in_sizes, int n_in,
                              void* d_out, int out_size, void* d_ws, size_t ws_size,
                              hipStream_t stream) {
    const float* r   = (const float*)d_in[0];
    const float* e   = (const float*)d_in[1];
    const float* Wf2 = (const float*)d_in[2];
    const float* bf2 = (const float*)d_in[3];
    const float* Wa  = (const float*)d_in[4];
    const float* W1  = (const float*)d_in[5];
    const float* b1  = (const float*)d_in[6];
    const float* W2  = (const float*)d_in[7];
    const float* b2  = (const float*)d_in[8];
    const int*   a   = (const int*)d_in[9];

    float* out = (float*)d_out;

    // workspace layout (4B words)
    uint32_t* rfb        = (uint32_t*)d_ws;              // rf bf16   [0, 3.2M)
    uint32_t* y1b        = (uint32_t*)d_ws + 3200000;    // y1 bf16   [3.2M, 6.4M)
    uint32_t* segb       = (uint32_t*)d_ws + 6400000;    // seg bf16  [6.4M, 9.6M)
    int*      counts     = (int*)d_ws + 9600000;         // NBIN
    int*      row_ptr    = counts + NBIN;                // NBIN
    int*      cursor     = row_ptr + NBIN;               // NBIN
    int*      chunk_sums = cursor + NBIN;                // 128
    uint32_t* sesq       = (uint32_t*)(chunk_sums + 128);// NE packed u16:u16
    __bf16*   pWaH       = (__bf16*)(sesq + NE);         // 6x16384 + 8192 bf16
    __bf16*   pWaL       = pWaH + 16384;
    __bf16*   pW1H       = pWaL + 16384;
    __bf16*   pW1L       = pW1H + 16384;
    __bf16*   pW2H       = pW1L + 16384;
    __bf16*   pW2L       = pW2H + 16384;
    __bf16*   pWf        = pW2L + 16384;

    // filter table (NTAB x 128 bf16 = 4.2MB) lives in d_out; dead before
    // dense2 overwrites d_out.
    __hip_bfloat16* wtab = (__hip_bfloat16*)d_out;

    (void)hipMemsetAsync(counts, 0, NBIN * sizeof(int), stream);
    pack_weights<<<64, 256, 0, stream>>>(Wa, W1, W2, Wf2,
                                         pWaH, pWaL, pW1H, pW1L, pW2H, pW2L, pWf);

    // hist (atomic) || rf-GEMM first half || filter-table build
    hist_rf<<<SCAT_BLKS + RF_BLKS + TAB_BLKS, 256, 0, stream>>>(
        a, counts, r, pWaH, pWaL, rfb, pWf, bf2, wtab);
    scanA<<<NCH, 512, 0, stream>>>(counts, chunk_sums);
    scanB<<<1, 128, 0, stream>>>(chunk_sums);
    scanC<<<NCH, 512, 0, stream>>>(counts, chunk_sums, row_ptr, cursor);
    // scatter (latency-bound) || rf-GEMM second half
    scatter_rf<<<SCAT_BLKS + RF_BLKS, 256, 0, stream>>>(a, e, cursor, sesq,
                                                        r, pWaH, pWaL, rfb);

    // edge pipeline v2: pure gather-fma against the filter table
    edge_fused<<<EGRID, 256, 0, stream>>>(sesq, row_ptr, (const uint32_t*)wtab,
                                          rfb, segb);

    // y1 = ssp(seg @ W1 + b1); out = y1 @ W2 + b2
    dense1<<<NTILE, 256, 0, stream>>>(segb, pW1H, pW1L, b1, y1b);
    dense2<<<NTILE, 256, 0, stream>>>(y1b, pW2H, pW2L, b2, out);
}

// Round 22
// 157.298 us; speedup vs baseline: 1.4854x; 1.2494x over previous
//
#include <hip/hip_runtime.h>
#include <hip/hip_bf16.h>
#include <math.h>

#define NA 50000
#define NE 800000
#define WPB 4                 // waves per block
#define NTILE 782             // 64-row tiles covering NA (dense kernels)
#define EGRID 2048            // edge blocks (8/CU)
#define NWAVES (EGRID * WPB)  // 8192 -> 6-7 dsts/wave
#define SCAT_BLKS 1024
#define RF_BLKS 782           // full rf-GEMM inside front_fused
#define TAB_BLKS 256          // 16384 table rows / 64
#define NTAB 16384            // 14-bit quantized e -> filter table rows
#define BCAP 64               // fixed bucket capacity per dst (max degree ~35)

typedef float f32x4 __attribute__((ext_vector_type(4)));
typedef __bf16 bf16x8 __attribute__((ext_vector_type(8)));

// softplus(x) - ln2, branch-free hw exp/log (R20: libm log1pf was a 77us wall)
__device__ __forceinline__ float ssp(float x) {
    float z  = __expf(-fabsf(x));
    float lp = __logf(1.0f + z);
    return fmaxf(x, 0.0f) + lp - 0.69314718f;
}

__device__ __forceinline__ uint32_t pkbf2(float a, float b) {
    union { __bf16 h[2]; uint32_t u; } x;
    x.h[0] = (__bf16)a; x.h[1] = (__bf16)b;
    return x.u;
}

// ---------------------------------------------------------------------------
// Pack weights into MFMA-B-fragment order (hi/lo bf16) + init bucket cursors.
// ---------------------------------------------------------------------------
__global__ __launch_bounds__(256) void pack_weights(const float* __restrict__ Wa,
                                                    const float* __restrict__ W1,
                                                    const float* __restrict__ W2,
                                                    const float* __restrict__ Wf2,
                                                    __bf16* __restrict__ pWaH, __bf16* __restrict__ pWaL,
                                                    __bf16* __restrict__ pW1H, __bf16* __restrict__ pW1L,
                                                    __bf16* __restrict__ pW2H, __bf16* __restrict__ pW2L,
                                                    __bf16* __restrict__ pWf,
                                                    int* __restrict__ cursor) {
    const int t = blockIdx.x * 256 + threadIdx.x;
    const int stride = gridDim.x * 256;
    for (int i = t; i < 16384; i += stride) {
        int k = i >> 7, n = i & 127;
        int addr = n * 128 + (((k >> 3) ^ (n & 15)) << 3) + (k & 7);
        float v; __bf16 h;
        v = Wa[i]; h = (__bf16)v; pWaH[addr] = h; pWaL[addr] = (__bf16)(v - (float)h);
        v = W1[i]; h = (__bf16)v; pW1H[addr] = h; pW1L[addr] = (__bf16)(v - (float)h);
        v = W2[i]; h = (__bf16)v; pW2H[addr] = h; pW2L[addr] = (__bf16)(v - (float)h);
    }
    for (int i = t; i < 8192; i += stride) {
        int k = i >> 7, n = i & 127;
        int addr = n * 64 + (((k >> 3) ^ (n & 7)) << 3) + (k & 7);
        pWf[addr] = (__bf16)Wf2[i];
    }
    for (int i = t; i < NA; i += stride) cursor[i] = i * BCAP;
}

// ---------------------------------------------------------------------------
// rf GEMM body with pre-packed weights (output packed bf16).
// ---------------------------------------------------------------------------
__device__ __forceinline__ void rf_gemm_packed(const float* __restrict__ A,
                                               const __bf16* __restrict__ pWh,
                                               const __bf16* __restrict__ pWl,
                                               void* __restrict__ C, int M,
                                               int blk, int gridn,
                                               __bf16* sWhi, __bf16* sWlo) {
    const int tid = threadIdx.x;
    {
        const uint4* ph = (const uint4*)pWh;
        const uint4* pl = (const uint4*)pWl;
        uint4* dh = (uint4*)sWhi;
        uint4* dl = (uint4*)sWlo;
        for (int i = tid; i < 2048; i += 256) { dh[i] = ph[i]; dl[i] = pl[i]; }
    }
    __syncthreads();

    const int lane = tid & 63, w = tid >> 6;
    const int lrow = lane & 15, lgrp = lane >> 4;

    for (int base = blk * 64; base < M; base += gridn * 64) {
        const int row  = base + w * 16 + lrow;
        const int rowc = row < M ? row : M - 1;

        f32x4 acc[8];
        #pragma unroll
        for (int nt = 0; nt < 8; ++nt) acc[nt] = (f32x4){0.f, 0.f, 0.f, 0.f};

        #pragma unroll
        for (int ks = 0; ks < 4; ++ks) {
            int k0 = ks * 32 + lgrp * 8;
            float4 f0 = *(const float4*)&A[(size_t)rowc * 128 + k0];
            float4 f1 = *(const float4*)&A[(size_t)rowc * 128 + k0 + 4];
            float av[8] = {f0.x, f0.y, f0.z, f0.w, f1.x, f1.y, f1.z, f1.w};
            bf16x8 ah, al;
            #pragma unroll
            for (int j = 0; j < 8; ++j) {
                __bf16 h = (__bf16)av[j];
                ah[j] = h;
                al[j] = (__bf16)(av[j] - (float)h);
            }
            #pragma unroll
            for (int nt = 0; nt < 8; ++nt) {
                int n = nt * 16 + lrow;
                int addr = n * 128 + (((ks * 4 + lgrp) ^ (n & 15)) << 3);
                bf16x8 bh = *(const bf16x8*)&sWhi[addr];
                bf16x8 bl = *(const bf16x8*)&sWlo[addr];
                acc[nt] = __builtin_amdgcn_mfma_f32_16x16x32_bf16(ah, bh, acc[nt], 0, 0, 0);
                acc[nt] = __builtin_amdgcn_mfma_f32_16x16x32_bf16(ah, bl, acc[nt], 0, 0, 0);
                acc[nt] = __builtin_amdgcn_mfma_f32_16x16x32_bf16(al, bh, acc[nt], 0, 0, 0);
            }
        }

        const int orow = base + w * 16 + lgrp * 4;
        #pragma unroll
        for (int r = 0; r < 4; ++r) {
            if (orow + r < M) {
                #pragma unroll
                for (int nt = 0; nt < 8; ++nt) {
                    ((__hip_bfloat16*)C)[(size_t)(orow + r) * 128 + nt * 16 + lrow] =
                        __float2bfloat16(acc[nt][r]);
                }
            }
        }
    }
}

// ---------------------------------------------------------------------------
// Filter-table build: Wtab[idx][f] = bf16( g(e_idx) @ Wf2_bf16 + bf2 ).
// ---------------------------------------------------------------------------
__device__ __forceinline__ void tab_build(const __bf16* __restrict__ pWf,
                                          const float* __restrict__ bf2,
                                          __hip_bfloat16* __restrict__ wtab,
                                          int blk, __bf16* sWf) {
    const int tid = threadIdx.x;
    {
        const uint4* p = (const uint4*)pWf;
        uint4* d = (uint4*)sWf;
        for (int i = tid; i < 1024; i += 256) d[i] = p[i];
    }
    __syncthreads();

    const int lane = tid & 63, w = tid >> 6;
    const int lrow = lane & 15, lgrp = lane >> 4;

    float bv[8];
    #pragma unroll
    for (int nt = 0; nt < 8; ++nt) bv[nt] = bf2[nt * 16 + lrow];

    const float coeff = -0.5f * (63.0f / 5.0f) * (63.0f / 5.0f);
    const int row = blk * 64 + w * 16 + lrow;
    const float ev = ((float)row * 4.0f + 1.5f) * (1.0f / 13107.0f);

    bf16x8 ah[2];
    #pragma unroll
    for (int ks = 0; ks < 2; ++ks) {
        #pragma unroll
        for (int j = 0; j < 8; ++j) {
            int k = ks * 32 + lgrp * 8 + j;
            float dd = ev - (5.0f / 63.0f) * (float)k;
            ah[ks][j] = (__bf16)__expf(coeff * dd * dd);
        }
    }

    f32x4 c[8];
    #pragma unroll
    for (int nt = 0; nt < 8; ++nt) c[nt] = (f32x4){0.f, 0.f, 0.f, 0.f};
    #pragma unroll
    for (int ks = 0; ks < 2; ++ks) {
        #pragma unroll
        for (int nt = 0; nt < 8; ++nt) {
            int n = nt * 16 + lrow;
            int addr = n * 64 + (((ks * 4 + lgrp) ^ (n & 7)) << 3);
            bf16x8 bh = *(const bf16x8*)&sWf[addr];
            c[nt] = __builtin_amdgcn_mfma_f32_16x16x32_bf16(ah[ks], bh, c[nt], 0, 0, 0);
        }
    }

    const int orow = blk * 64 + w * 16 + lgrp * 4;
    #pragma unroll
    for (int r = 0; r < 4; ++r) {
        #pragma unroll
        for (int nt = 0; nt < 8; ++nt) {
            wtab[(size_t)(orow + r) * 128 + nt * 16 + lrow] =
                __float2bfloat16(c[nt][r] + bv[nt]);
        }
    }
}

// ---------------------------------------------------------------------------
// front_fused: bucket scatter (atomic/latency) || FULL rf-GEMM || table build.
// No hist, no scans -- fixed-capacity buckets (cursor pre-set to d*BCAP).
// ---------------------------------------------------------------------------
__global__ __launch_bounds__(256) void front_fused(const int* __restrict__ a,
                                                   const float* __restrict__ e,
                                                   int* __restrict__ cursor,
                                                   uint32_t* __restrict__ bucket,
                                                   const float* __restrict__ r,
                                                   const __bf16* __restrict__ pWaH,
                                                   const __bf16* __restrict__ pWaL,
                                                   void* __restrict__ rfb,
                                                   const __bf16* __restrict__ pWf,
                                                   const float* __restrict__ bf2,
                                                   __hip_bfloat16* __restrict__ wtab) {
    __shared__ __bf16 sWhi[128 * 128];
    __shared__ __bf16 sWlo[128 * 128];
    if (blockIdx.x < SCAT_BLKS) {
        for (int i = blockIdx.x * 256 + threadIdx.x; i < NE; i += SCAT_BLKS * 256) {
            int2 dp = ((const int2*)a)[i];
            int pos = atomicAdd(&cursor[dp.x], 1);
            uint32_t eq = (uint32_t)(e[i] * 13107.0f + 0.5f);   // 65535/5
            if (pos < dp.x * BCAP + BCAP)                       // overflow guard
                bucket[pos] = (eq << 16) | (uint32_t)dp.y;
        }
    } else if (blockIdx.x < SCAT_BLKS + RF_BLKS) {
        rf_gemm_packed(r, pWaH, pWaL, rfb, NA, blockIdx.x - SCAT_BLKS,
                       RF_BLKS, sWhi, sWlo);
    } else {
        tab_build(pWf, bf2, wtab, blockIdx.x - SCAT_BLKS - RF_BLKS, sWhi);
    }
}

// ---------------------------------------------------------------------------
// Edge pipeline v3: per-dst gather-fma over fixed buckets. Per dst: stage the
// 64-slot bucket row (coalesced) -> batched 16-deep rfb/wtab row gathers ->
// fma -> one segb store. No CSR, no boundary walk, no MFMA, ~1.2KB LDS.
// ---------------------------------------------------------------------------
__global__ __launch_bounds__(256, 8) void edge_fused(const int* __restrict__ cursor,
                                                     const uint32_t* __restrict__ bucket,
                                                     const uint32_t* __restrict__ wtab,
                                                     const uint32_t* __restrict__ rfb,
                                                     uint32_t* __restrict__ segb) {
    __shared__ uint32_t su[WPB][BCAP];
    __shared__ int      scnt[WPB][8];

    const int tid  = threadIdx.x;
    const int lane = tid & 63, w = tid >> 6;

    const int wi      = blockIdx.x * WPB + w;
    const int d_start = (int)(((long long)wi * NA) / NWAVES);
    const int d_end   = (int)(((long long)(wi + 1) * NA) / NWAVES);
    const int dcount  = d_end - d_start;            // 6 or 7

    if (lane < dcount) {
        int c = cursor[d_start + lane] - (d_start + lane) * BCAP;
        scnt[w][lane] = (c < BCAP) ? c : BCAP;
    }
    __builtin_amdgcn_wave_barrier();

    uint32_t* su_w = su[w];

    for (int di = 0; di < dcount; ++di) {
        const int d   = d_start + di;
        const int cnt = scnt[w][di];

        su_w[lane] = bucket[(size_t)d * BCAP + lane];   // coalesced 256B stage
        __builtin_amdgcn_wave_barrier();

        float racc0 = 0.0f, racc1 = 0.0f;
        for (int j0 = 0; j0 < cnt; j0 += 16) {
            uint32_t rw[16], tw[16];
            #pragma unroll
            for (int j = 0; j < 16; ++j) {
                int jj = (j0 + j < cnt) ? (j0 + j) : (cnt - 1);   // clamp
                uint32_t u = su_w[jj];
                rw[j] = rfb[(size_t)(u & 0xFFFFu) * 64 + lane];
                tw[j] = wtab[(size_t)(u >> 18) * 64 + lane];
            }
            #pragma unroll
            for (int j = 0; j < 16; ++j) {
                if (j0 + j < cnt) {                     // wave-uniform
                    racc0 = fmaf(__uint_as_float(rw[j] << 16),
                                 __uint_as_float(tw[j] << 16), racc0);
                    racc1 = fmaf(__uint_as_float(rw[j] & 0xFFFF0000u),
                                 __uint_as_float(tw[j] & 0xFFFF0000u), racc1);
                }
            }
        }
        segb[(size_t)d * 64 + lane] = pkbf2(racc0, racc1);
        __builtin_amdgcn_wave_barrier();                // before su_w reuse
    }
}

// ---------------------------------------------------------------------------
// Dense1: y1 = ssp(seg @ W1 + b1). A = packed-bf16 seg (ws), direct bf16x8.
// ---------------------------------------------------------------------------
__global__ __launch_bounds__(256) void dense1(const uint32_t* __restrict__ segb,
                                              const __bf16* __restrict__ pW1H,
                                              const __bf16* __restrict__ pW1L,
                                              const float* __restrict__ b1,
                                              void* __restrict__ y1b) {
    __shared__ __bf16 sWhi[128 * 128];
    __shared__ __bf16 sWlo[128 * 128];
    const int tid = threadIdx.x;
    {
        const uint4* ph = (const uint4*)pW1H;
        const uint4* pl = (const uint4*)pW1L;
        uint4* dh = (uint4*)sWhi;
        uint4* dl = (uint4*)sWlo;
        for (int i = tid; i < 2048; i += 256) { dh[i] = ph[i]; dl[i] = pl[i]; }
    }
    __syncthreads();

    const int lane = tid & 63, w = tid >> 6;
    const int lrow = lane & 15, lgrp = lane >> 4;
    const __bf16* seg = (const __bf16*)segb;

    float bv[8];
    #pragma unroll
    for (int nt = 0; nt < 8; ++nt) bv[nt] = b1[nt * 16 + lrow];

    const int base = blockIdx.x * 64;
    const int row  = base + w * 16 + lrow;
    const int rowc = row < NA ? row : NA - 1;

    f32x4 acc[8];
    #pragma unroll
    for (int nt = 0; nt < 8; ++nt) acc[nt] = (f32x4){0.f, 0.f, 0.f, 0.f};

    #pragma unroll
    for (int ks = 0; ks < 4; ++ks) {
        int k0 = ks * 32 + lgrp * 8;
        bf16x8 ya = *(const bf16x8*)&seg[(size_t)rowc * 128 + k0];
        #pragma unroll
        for (int nt = 0; nt < 8; ++nt) {
            int n = nt * 16 + lrow;
            int addr = n * 128 + (((ks * 4 + lgrp) ^ (n & 15)) << 3);
            bf16x8 bh = *(const bf16x8*)&sWhi[addr];
            bf16x8 bl = *(const bf16x8*)&sWlo[addr];
            acc[nt] = __builtin_amdgcn_mfma_f32_16x16x32_bf16(ya, bh, acc[nt], 0, 0, 0);
            acc[nt] = __builtin_amdgcn_mfma_f32_16x16x32_bf16(ya, bl, acc[nt], 0, 0, 0);
        }
    }

    const int orow = base + w * 16 + lgrp * 4;
    #pragma unroll
    for (int r = 0; r < 4; ++r) {
        if (orow + r < NA) {
            #pragma unroll
            for (int nt = 0; nt < 8; ++nt) {
                float v = ssp(acc[nt][r] + bv[nt]);
                ((__hip_bfloat16*)y1b)[(size_t)(orow + r) * 128 + nt * 16 + lrow] =
                    __float2bfloat16(v);
            }
        }
    }
}

// ---------------------------------------------------------------------------
// Dense2: out = y1 @ W2 + b2. Only writer of d_out (wtab/bucket dead by now).
// ---------------------------------------------------------------------------
__global__ __launch_bounds__(256) void dense2(const void* __restrict__ y1b,
                                              const __bf16* __restrict__ pW2H,
                                              const __bf16* __restrict__ pW2L,
                                              const float* __restrict__ b2,
                                              float* __restrict__ out) {
    __shared__ __bf16 sWhi[128 * 128];
    __shared__ __bf16 sWlo[128 * 128];
    const int tid = threadIdx.x;
    {
        const uint4* ph = (const uint4*)pW2H;
        const uint4* pl = (const uint4*)pW2L;
        uint4* dh = (uint4*)sWhi;
        uint4* dl = (uint4*)sWlo;
        for (int i = tid; i < 2048; i += 256) { dh[i] = ph[i]; dl[i] = pl[i]; }
    }
    __syncthreads();

    const int lane = tid & 63, w = tid >> 6;
    const int lrow = lane & 15, lgrp = lane >> 4;
    const __bf16* y1 = (const __bf16*)y1b;

    float bv[8];
    #pragma unroll
    for (int nt = 0; nt < 8; ++nt) bv[nt] = b2[nt * 16 + lrow];

    const int base = blockIdx.x * 64;
    const int row  = base + w * 16 + lrow;
    const int rowc = row < NA ? row : NA - 1;

    f32x4 acc[8];
    #pragma unroll
    for (int nt = 0; nt < 8; ++nt) acc[nt] = (f32x4){0.f, 0.f, 0.f, 0.f};

    #pragma unroll
    for (int ks = 0; ks < 4; ++ks) {
        int k0 = ks * 32 + lgrp * 8;
        bf16x8 ya = *(const bf16x8*)&y1[(size_t)rowc * 128 + k0];
        #pragma unroll
        for (int nt = 0; nt < 8; ++nt) {
            int n = nt * 16 + lrow;
            int addr = n * 128 + (((ks * 4 + lgrp) ^ (n & 15)) << 3);
            bf16x8 bh = *(const bf16x8*)&sWhi[addr];
            bf16x8 bl = *(const bf16x8*)&sWlo[addr];
            acc[nt] = __builtin_amdgcn_mfma_f32_16x16x32_bf16(ya, bh, acc[nt], 0, 0, 0);
            acc[nt] = __builtin_amdgcn_mfma_f32_16x16x32_bf16(ya, bl, acc[nt], 0, 0, 0);
        }
    }

    const int orow = base + w * 16 + lgrp * 4;
    #pragma unroll
    for (int r = 0; r < 4; ++r) {
        if (orow + r < NA) {
            #pragma unroll
            for (int nt = 0; nt < 8; ++nt) {
                out[(size_t)(orow + r) * 128 + nt * 16 + lrow] = acc[nt][r] + bv[nt];
            }
        }
    }
}

extern "C" void kernel_launch(void* const* d_in, const int* in_sizes, int n_in,
                              void* d_out, int out_size, void* d_ws, size_t ws_size,
                              hipStream_t stream) {
    const float* r   = (const float*)d_in[0];
    const float* e   = (const float*)d_in[1];
    const float* Wf2 = (const float*)d_in[2];
    const float* bf2 = (const float*)d_in[3];
    const float* Wa  = (const float*)d_in[4];
    const float* W1  = (const float*)d_in[5];
    const float* b1  = (const float*)d_in[6];
    const float* W2  = (const float*)d_in[7];
    const float* b2  = (const float*)d_in[8];
    const int*   a   = (const int*)d_in[9];

    float* out = (float*)d_out;

    // workspace layout (4B words)
    uint32_t* rfb    = (uint32_t*)d_ws;                  // rf bf16   [0, 3.2M)
    uint32_t* y1b    = (uint32_t*)d_ws + 3200000;        // y1 bf16   [3.2M, 6.4M)
    uint32_t* segb   = (uint32_t*)d_ws + 6400000;        // seg bf16  [6.4M, 9.6M)
    int*      cursor = (int*)d_ws + 9600000;             // NA cursors
    __bf16*   pWaH   = (__bf16*)((int*)d_ws + 9650048);  // weights (bf16)
    __bf16*   pWaL   = pWaH + 16384;
    __bf16*   pW1H   = pWaL + 16384;
    __bf16*   pW1L   = pW1H + 16384;
    __bf16*   pW2H   = pW1L + 16384;
    __bf16*   pW2L   = pW2H + 16384;
    __bf16*   pWf    = pW2L + 16384;

    // d_out scratch: wtab [0, 1.05M words), bucket [1.31M, 4.51M words).
    // Both dead before dense2 overwrites d_out.
    __hip_bfloat16* wtab   = (__hip_bfloat16*)d_out;
    uint32_t*       bucket = (uint32_t*)d_out + 1310720;

    pack_weights<<<64, 256, 0, stream>>>(Wa, W1, W2, Wf2,
                                         pWaH, pWaL, pW1H, pW1L, pW2H, pW2L,
                                         pWf, cursor);

    // bucket scatter || full rf-GEMM || filter-table build (one launch)
    front_fused<<<SCAT_BLKS + RF_BLKS + TAB_BLKS, 256, 0, stream>>>(
        a, e, cursor, bucket, r, pWaH, pWaL, rfb, pWf, bf2, wtab);

    // edge pipeline v3: per-dst gather-fma over fixed buckets
    edge_fused<<<EGRID, 256, 0, stream>>>(cursor, bucket, (const uint32_t*)wtab,
                                          rfb, segb);

    // y1 = ssp(seg @ W1 + b1); out = y1 @ W2 + b2
    dense1<<<NTILE, 256, 0, stream>>>(segb, pW1H, pW1L, b1, y1b);
    dense2<<<NTILE, 256, 0, stream>>>(y1b, pW2H, pW2L, b2, out);
}